// Round 9
// baseline (685.991 us; speedup 1.0000x reference)
//
#include <hip/hip_runtime.h>
#include <hip/hip_bf16.h>

#define Vn   196608
#define NNZn 1769472
#define Bn   4
#define Pn   64
#define Qn   64
#define VPn  (Vn*Pn)

typedef __hip_bfloat16 bf16;
typedef __attribute__((ext_vector_type(8))) short bf16x8;
typedef __attribute__((ext_vector_type(4))) float f32x4;
typedef __attribute__((ext_vector_type(4))) unsigned int u32x4;

__device__ inline short f2bs(float f){
  __hip_bfloat16 h = __float2bfloat16(f);
  return *(short*)&h;
}
__device__ inline float lo16(unsigned u){ return __uint_as_float(u<<16); }
__device__ inline float hi16(unsigned u){ return __uint_as_float(u & 0xffff0000u); }

// ---------------- CSR build (counting sort) ----------------

__global__ void k_zero(unsigned* __restrict__ p, int n){
  int i = blockIdx.x*blockDim.x + threadIdx.x;
  if(i<n) p[i]=0u;
}

// ---- fused pre-pass: hist (latency-bound) + cvt (streaming) + prepw -------
// Block-uniform role selection; hist blocks interleaved 1-in-15 so every CU
// holds a mix of waiting-on-atomic waves and streaming waves.

__global__ void k_pre(const int* __restrict__ rows, unsigned* __restrict__ counts,
                      const float* __restrict__ x, short* __restrict__ x0c,
                      const float* __restrict__ wf, short* __restrict__ wcb){
  const int bid = blockIdx.x;
  int h=-1, f=-1;
  if(bid < 25920){
    if(bid%15==0) h = bid/15;
    else          f = 14*(bid/15) + (bid%15) - 1;
  } else {
    f = 24192 + (bid - 25920);
  }
  if(h >= 0){                      // ---- hist: 4 independent atomic chains
    const int i = (h*256 + threadIdx.x)*4;
    const int4 r = *(const int4*)(rows + i);
    atomicAdd(&counts[r.x], 1u);
    atomicAdd(&counts[r.y], 1u);
    atomicAdd(&counts[r.z], 1u);
    atomicAdd(&counts[r.w], 1u);
  } else if(f < 24576){            // ---- cvt: 8 floats -> 8 bf16 per thread
    const int i = f*256 + threadIdx.x;
    const int o = i*8;
    const int v = o>>8, bp = o&255;
    const int hh = bp>>7, w7 = bp&127;
    const int b = (hh<<1) + (w7>>6), p = w7&63;
    const float* xp = x + (size_t)b*VPn + (size_t)v*64 + p;
    const float4 f0 = *(const float4*)xp;
    const float4 f1 = *(const float4*)(xp+4);
    unsigned r0 = ((unsigned)(unsigned short)f2bs(f0.y)<<16) | (unsigned)(unsigned short)f2bs(f0.x);
    unsigned r1 = ((unsigned)(unsigned short)f2bs(f0.w)<<16) | (unsigned)(unsigned short)f2bs(f0.z);
    unsigned r2 = ((unsigned)(unsigned short)f2bs(f1.y)<<16) | (unsigned)(unsigned short)f2bs(f1.x);
    unsigned r3 = ((unsigned)(unsigned short)f2bs(f1.w)<<16) | (unsigned)(unsigned short)f2bs(f1.z);
    u32x4 u; u[0]=r0; u[1]=r1; u[2]=r2; u[3]=r3;
    *(u32x4*)(x0c + ((size_t)hh*Vn + v)*128 + w7) = u;
  } else {                         // ---- prepw: combined weights wcb[q][192]
    const int idx = (f - 24576)*256 + threadIdx.x;   // 12288 total
    const int q = idx/192, rem = idx%192, part = rem>>6, p = rem&63;
    float w;
    if(part==0)      w = wf[(3*p+0)*64+q] - wf[(3*p+2)*64+q];
    else if(part==1) w = wf[(3*p+1)*64+q];
    else             w = 2.0f*wf[(3*p+2)*64+q];
    wcb[idx] = f2bs(w);
  }
}

__global__ __launch_bounds__(1024) void k_scan_block(const unsigned* __restrict__ counts,
                                                     unsigned* __restrict__ incl,
                                                     unsigned* __restrict__ bsums){
  __shared__ unsigned s[1024];
  const int tid = threadIdx.x;
  const int gid = blockIdx.x*1024 + tid;
  s[tid] = counts[gid];
  __syncthreads();
  for(int off=1; off<1024; off<<=1){
    unsigned v = (tid>=off) ? s[tid-off] : 0u;
    __syncthreads();
    s[tid] += v;
    __syncthreads();
  }
  incl[gid] = s[tid];
  if(tid==1023) bsums[blockIdx.x] = s[1023];
}

__global__ void k_scan_top(unsigned* __restrict__ bs){
  __shared__ unsigned t[192];
  const int i = threadIdx.x;                 // 256 threads
  if(i<192) t[i]=bs[i];
  __syncthreads();
  for(int off=1; off<192; off<<=1){
    unsigned v = (i>=off && i<192) ? t[i-off] : 0u;
    __syncthreads();
    if(i<192) t[i] += v;
    __syncthreads();
  }
  if(i<192) bs[i] = (i==0) ? 0u : t[i-1];   // exclusive
}

__global__ void k_scan_add(const unsigned* __restrict__ counts, unsigned* __restrict__ incl,
                           const unsigned* __restrict__ boffs,
                           unsigned* __restrict__ rstart, unsigned* __restrict__ cursor){
  int i = blockIdx.x*blockDim.x + threadIdx.x;   // grid covers V exactly
  unsigned e = incl[i] + boffs[i>>10];
  incl[i] = e;
  unsigned st = e - counts[i];
  rstart[i] = st;
  cursor[i] = st;
}

// 1 edge/thread (R5-proven shape: max wave count, best atomic pipelining).
__global__ void k_scatter(const float* __restrict__ vals, const int* __restrict__ rows,
                          const int* __restrict__ cols, unsigned* __restrict__ cursor,
                          int2* __restrict__ meta){
  int i = blockIdx.x*blockDim.x + threadIdx.x;   // grid covers NNZ exactly
  int r = rows[i];
  unsigned pos = atomicAdd(&cursor[r], 1u);
  int2 m; m.x = cols[i]; m.y = __float_as_int(vals[i]);
  meta[pos] = m;
}

// ---------------- gather pipeline macros (R5-proven) ----------------

#define SP_STAGE(U,W,I) { int c_=0; float wv_=0.f; \
    if((I) < n){ const int2 m_ = meta[s+(unsigned)(I)]; c_=m_.x; wv_=__int_as_float(m_.y);} \
    W = wv_; U = *(const u32x4*)(src + (size_t)c_*SROW + off); }
#define SP_CONSUME(U,W) { \
    a0=fmaf(W,lo16(U[0]),a0); a1=fmaf(W,hi16(U[0]),a1); \
    a2=fmaf(W,lo16(U[1]),a2); a3=fmaf(W,hi16(U[1]),a3); \
    a4=fmaf(W,lo16(U[2]),a4); a5=fmaf(W,hi16(U[2]),a5); \
    a6=fmaf(W,lo16(U[3]),a6); a7=fmaf(W,hi16(U[3]),a7); }
#define SP_BODY \
  float a0=0,a1=0,a2=0,a3=0,a4=0,a5=0,a6=0,a7=0; \
  if(nmax > 0){ \
    u32x4 u0,u1,u2,u3; float w0,w1,w2,w3; \
    SP_STAGE(u0,w0,0) SP_STAGE(u1,w1,1) SP_STAGE(u2,w2,2) SP_STAGE(u3,w3,3) \
    int rem = nmax - 4; \
    int j = 4; \
    while(rem > 0){ \
      const u32x4 p0=u0, p1=u1, p2=u2, p3=u3; \
      const float q0=w0, q1=w1, q2=w2, q3=w3; \
      SP_STAGE(u0,w0,j) SP_STAGE(u1,w1,j+1) SP_STAGE(u2,w2,j+2) SP_STAGE(u3,w3,j+3) \
      SP_CONSUME(p0,q0) SP_CONSUME(p1,q1) SP_CONSUME(p2,q2) SP_CONSUME(p3,q3) \
      rem -= 4; j += 4; \
    } \
    SP_CONSUME(u0,w0) SP_CONSUME(u1,w1) SP_CONSUME(u2,w2) SP_CONSUME(u3,w3) \
  } \
  unsigned r0 = ((unsigned)(unsigned short)f2bs(a1)<<16) | (unsigned)(unsigned short)f2bs(a0); \
  unsigned r1 = ((unsigned)(unsigned short)f2bs(a3)<<16) | (unsigned)(unsigned short)f2bs(a2); \
  unsigned r2 = ((unsigned)(unsigned short)f2bs(a5)<<16) | (unsigned)(unsigned short)f2bs(a4); \
  unsigned r3 = ((unsigned)(unsigned short)f2bs(a7)<<16) | (unsigned)(unsigned short)f2bs(a6); \
  u32x4 ov; ov[0]=r0; ov[1]=r1; ov[2]=r2; ov[3]=r3;

// ---------------- SpMM1: TWO rows per wave (one per half-wave) --------------

template<int SROW, size_t PSTR>
__global__ __launch_bounds__(256) void k_spmm(const short* __restrict__ src,
                          const int2* __restrict__ meta,
                          const unsigned* __restrict__ rstart, const unsigned* __restrict__ rend,
                          short* __restrict__ dst){
  const int tid = threadIdx.x;
  const int lane = tid & 63;
  const int half = lane >> 5, sub = lane & 31;
  const int vbase = blockIdx.x*8 + (tid>>6)*2;
  const unsigned sA = rstart[vbase],   sB = rstart[vbase+1];
  const int nA = (int)(rend[vbase]-sA), nB = (int)(rend[vbase+1]-sB);
  const int nmax = (nA > nB) ? nA : nB;
  const unsigned s = half ? sB : sA;
  const int n = half ? nB : nA;
  const size_t off = (size_t)(sub>>4)*PSTR + (size_t)((sub&15)*8);
  SP_BODY
  *(u32x4*)(dst + (size_t)(vbase+half)*256 + sub*8) = ov;
}

// ---------------- fused SpMM2 + MFMA GEMM (8-row slab, 2 rounds) ----------
// Each wave owns 16 output rows, barrier-free. Per round (2): gather 8 y-rows
// (L@x1, half-wave per row, depth-4 pipeline) into a wave-private 8-row LDS
// slab (4224 B/wave), then run part-2 MFMAs with out-of-round A-rows zeroed
// per-lane. Part-0/1 MFMAs stream x0c/x1 directly. LDS 16896 B/block ->
// occupancy VGPR-bound (~75% static) instead of LDS-bound (50%).
// mfma_f32_16x16x32_bf16: A row=l&15, k=8*(l>>4)+i; C/D col=l&15, row=4*(l>>4)+reg.
// x0c-in-d_out aliasing safe: wave reads x0c only for its own 16 rows and is
// the only writer of those out rows; per-wave program order orders them.

__global__ __launch_bounds__(256) void k_gemm_fused(
    const short* __restrict__ x0, const short* __restrict__ x1,
    const short* __restrict__ wcb, const float* __restrict__ bias,
    const int2* __restrict__ meta, const unsigned* __restrict__ rstart,
    const unsigned* __restrict__ rend, float* __restrict__ out){
  __shared__ short ylds[4][8*264];
  const int t = threadIdx.x, w = t>>6, l = t&63;
  const int half = l>>5, sub = l&31;
  const int vw = blockIdx.x*64 + w*16;
  short* const my = &ylds[w][0];
  const short* const src = x1;
  const int SROW = 256;
  const size_t off = (size_t)(sub>>4)*128 + (size_t)((sub&15)*8);
  const int r = l&15, g = l>>4;
  f32x4 acc[4][4] = {};   // [batch][n]

  // ---- part 0 + part 1 (c=0..3): stream x0c / x1 rows ----
#pragma unroll
  for(int c=0; c<4; ++c){
    const int part = c>>1, ko = (c&1)*32;
    const int kw = part*64 + ko + 8*g;
    const bf16x8 bfr0 = *(const bf16x8*)&wcb[( 0+r)*192 + kw];
    const bf16x8 bfr1 = *(const bf16x8*)&wcb[(16+r)*192 + kw];
    const bf16x8 bfr2 = *(const bf16x8*)&wcb[(32+r)*192 + kw];
    const bf16x8 bfr3 = *(const bf16x8*)&wcb[(48+r)*192 + kw];
#pragma unroll
    for(int bb=0; bb<4; ++bb){
      bf16x8 a;
      if(part==0) a = *(const bf16x8*)(x0 + ((size_t)(bb>>1)*Vn + vw + r)*128 + (bb&1)*64 + ko + 8*g);
      else        a = *(const bf16x8*)(x1 + ((size_t)(vw + r))*256 + bb*64 + ko + 8*g);
      acc[bb][0] = __builtin_amdgcn_mfma_f32_16x16x32_bf16(a, bfr0, acc[bb][0], 0, 0, 0);
      acc[bb][1] = __builtin_amdgcn_mfma_f32_16x16x32_bf16(a, bfr1, acc[bb][1], 0, 0, 0);
      acc[bb][2] = __builtin_amdgcn_mfma_f32_16x16x32_bf16(a, bfr2, acc[bb][2], 0, 0, 0);
      acc[bb][3] = __builtin_amdgcn_mfma_f32_16x16x32_bf16(a, bfr3, acc[bb][3], 0, 0, 0);
    }
  }

  // ---- part 2 in two rounds of 8 gathered rows ----
#pragma unroll
  for(int rd=0; rd<2; ++rd){
    // gather 8 y-rows (4 pairs, half-wave per row) into the slab
    for(int pr=0; pr<4; ++pr){
      const int vb = vw + rd*8 + pr*2;
      const unsigned sA = rstart[vb], sB = rstart[vb+1];
      const int nA = (int)(rend[vb]-sA), nB = (int)(rend[vb+1]-sB);
      const int nmax = (nA > nB) ? nA : nB;
      const unsigned s = half ? sB : sA;
      const int n = half ? nB : nA;
      SP_BODY
      *(u32x4*)(my + (pr*2+half)*264 + off) = ov;
    }
    // part-2 MFMAs for this round (A zeroed for rows outside the round)
#pragma unroll
    for(int cc=0; cc<2; ++cc){
      const int ko = cc*32;
      const int kw = 128 + ko + 8*g;
      const bf16x8 bfr0 = *(const bf16x8*)&wcb[( 0+r)*192 + kw];
      const bf16x8 bfr1 = *(const bf16x8*)&wcb[(16+r)*192 + kw];
      const bf16x8 bfr2 = *(const bf16x8*)&wcb[(32+r)*192 + kw];
      const bf16x8 bfr3 = *(const bf16x8*)&wcb[(48+r)*192 + kw];
      const bool live = (r>>3) == rd;
#pragma unroll
      for(int bb=0; bb<4; ++bb){
        bf16x8 a = *(const bf16x8*)(my + (r&7)*264 + bb*64 + ko + 8*g);
        if(!live){ bf16x8 zz = {}; a = zz; }
        acc[bb][0] = __builtin_amdgcn_mfma_f32_16x16x32_bf16(a, bfr0, acc[bb][0], 0, 0, 0);
        acc[bb][1] = __builtin_amdgcn_mfma_f32_16x16x32_bf16(a, bfr1, acc[bb][1], 0, 0, 0);
        acc[bb][2] = __builtin_amdgcn_mfma_f32_16x16x32_bf16(a, bfr2, acc[bb][2], 0, 0, 0);
        acc[bb][3] = __builtin_amdgcn_mfma_f32_16x16x32_bf16(a, bfr3, acc[bb][3], 0, 0, 0);
      }
    }
  }

  // ---- epilogue ----
#pragma unroll
  for(int bb=0; bb<4; ++bb){
    float* ob = out + (size_t)bb*Vn*64;
#pragma unroll
    for(int n=0; n<4; ++n){
      const float bq = bias[n*16+r];
#pragma unroll
      for(int reg=0; reg<4; ++reg)
        ob[(size_t)(vw + g*4 + reg)*64 + n*16 + r] = acc[bb][n][reg] + bq;
    }
  }
}

// ---------------- launch ----------------

extern "C" void kernel_launch(void* const* d_in, const int* in_sizes, int n_in,
                              void* d_out, int out_size, void* d_ws, size_t ws_size,
                              hipStream_t stream){
  const float* lap_vals = (const float*)d_in[0];
  const float* x        = (const float*)d_in[1];
  const float* weight   = (const float*)d_in[2];
  const float* bias     = (const float*)d_in[3];
  const int*   lap_rows = (const int*)d_in[4];
  const int*   lap_cols = (const int*)d_in[5];
  float* out = (float*)d_out;
  short* x0c = (short*)d_out;   // bf16 x0 staged inside the output buffer

  char* w = (char*)d_ws;
  short* x1b = (short*)w;          w += (size_t)Vn*256*sizeof(short);
  int2* meta = (int2*)w;           w += (size_t)NNZn*8;
  unsigned* counts = (unsigned*)w; w += (size_t)Vn*4;
  unsigned* cursor = (unsigned*)w; w += (size_t)Vn*4;
  unsigned* rstart = (unsigned*)w; w += (size_t)Vn*4;
  unsigned* rend   = (unsigned*)w; w += (size_t)Vn*4;
  unsigned* bsums  = (unsigned*)w; w += 1024;
  short* wcb = (short*)w;          w += 12288*sizeof(short);

  k_zero<<<Vn/256, 256, 0, stream>>>(counts, Vn);
  k_pre<<<26352, 256, 0, stream>>>(lap_rows, counts, x, x0c, weight, wcb);
  k_scan_block<<<192, 1024, 0, stream>>>(counts, rend, bsums);
  k_scan_top<<<1, 256, 0, stream>>>(bsums);
  k_scan_add<<<Vn/256, 256, 0, stream>>>(counts, rend, bsums, rstart, cursor);
  k_scatter<<<NNZn/256, 256, 0, stream>>>(lap_vals, lap_rows, lap_cols, cursor, meta);

  // x1 = L @ x0   (gather from x0c: piece-split rows, 2 x 256B segments)
  k_spmm<128, (size_t)Vn*128><<<Vn/8, 256, 0, stream>>>(x0c, meta, rstart, rend, x1b);

  // fused: y-gather (L @ x1) + MFMA epilogue
  k_gemm_fused<<<Vn/64, 256, 0, stream>>>(x0c, x1b, wcb, bias,
                                          meta, rstart, rend, out);
}

// Round 10
// 525.970 us; speedup vs baseline: 1.3042x; 1.3042x over previous
//
#include <hip/hip_runtime.h>
#include <hip/hip_bf16.h>

#define Vn   196608
#define NNZn 1769472
#define Bn   4
#define Pn   64
#define Qn   64
#define VPn  (Vn*Pn)
#define NB   256      // buckets
#define RPB  768      // rows per bucket = Vn/NB
#define EPT  4096     // edges per count/bucket tile
#define NTIL 432      // NNZ/EPT

typedef __hip_bfloat16 bf16;
typedef __attribute__((ext_vector_type(8))) short bf16x8;
typedef __attribute__((ext_vector_type(4))) float f32x4;
typedef __attribute__((ext_vector_type(4))) unsigned int u32x4;

__device__ inline short f2bs(float f){
  __hip_bfloat16 h = __float2bfloat16(f);
  return *(short*)&h;
}
__device__ inline float lo16(unsigned u){ return __uint_as_float(u<<16); }
__device__ inline float hi16(unsigned u){ return __uint_as_float(u & 0xffff0000u); }

// ---------------- tiny init ----------------
__global__ void k_zero256(unsigned* __restrict__ g){ g[threadIdx.x] = 0u; }

// ---- fused pre-pass: bucket-count (LDS-aggregated) + cvt + prepw ----------
// count blocks interleaved 1-in-58 with streaming cvt blocks.
// grid = 432*58 = 25056; non-count f in [0,24624): cvt<24576, prepw 48.

__global__ __launch_bounds__(256) void k_pre(const int* __restrict__ rows, unsigned* __restrict__ gcount,
                      const float* __restrict__ x, short* __restrict__ x0c,
                      const float* __restrict__ wf, short* __restrict__ wcb){
  __shared__ unsigned hcnt[NB];
  const int bid = blockIdx.x, t = threadIdx.x;
  if(bid % 58 == 0){               // ---- count: LDS hist over 256 buckets
    const int cb = bid/58;
    hcnt[t] = 0u;
    __syncthreads();
    const int base = cb*EPT;
#pragma unroll
    for(int k=0;k<4;++k){
      const int4 r = *(const int4*)(rows + base + k*1024 + t*4);
      atomicAdd(&hcnt[(unsigned)r.x/RPB], 1u);
      atomicAdd(&hcnt[(unsigned)r.y/RPB], 1u);
      atomicAdd(&hcnt[(unsigned)r.z/RPB], 1u);
      atomicAdd(&hcnt[(unsigned)r.w/RPB], 1u);
    }
    __syncthreads();
    atomicAdd(&gcount[t], hcnt[t]);
    return;
  }
  const int f = bid - bid/58 - 1;
  if(f < 24576){                   // ---- cvt: 8 floats -> 8 bf16 per thread
    const int i = f*256 + t;
    const int o = i*8;
    const int v = o>>8, bp = o&255;
    const int hh = bp>>7, w7 = bp&127;
    const int b = (hh<<1) + (w7>>6), p = w7&63;
    const float* xp = x + (size_t)b*VPn + (size_t)v*64 + p;
    const float4 f0 = *(const float4*)xp;
    const float4 f1 = *(const float4*)(xp+4);
    unsigned r0 = ((unsigned)(unsigned short)f2bs(f0.y)<<16) | (unsigned)(unsigned short)f2bs(f0.x);
    unsigned r1 = ((unsigned)(unsigned short)f2bs(f0.w)<<16) | (unsigned)(unsigned short)f2bs(f0.z);
    unsigned r2 = ((unsigned)(unsigned short)f2bs(f1.y)<<16) | (unsigned)(unsigned short)f2bs(f1.x);
    unsigned r3 = ((unsigned)(unsigned short)f2bs(f1.w)<<16) | (unsigned)(unsigned short)f2bs(f1.z);
    u32x4 u; u[0]=r0; u[1]=r1; u[2]=r2; u[3]=r3;
    *(u32x4*)(x0c + ((size_t)hh*Vn + v)*128 + w7) = u;
  } else {                         // ---- prepw: combined weights wcb[q][192]
    const int idx = (f - 24576)*256 + t;         // 12288 total
    const int q = idx/192, rem = idx%192, part = rem>>6, p = rem&63;
    float w;
    if(part==0)      w = wf[(3*p+0)*64+q] - wf[(3*p+2)*64+q];
    else if(part==1) w = wf[(3*p+1)*64+q];
    else             w = 2.0f*wf[(3*p+2)*64+q];
    wcb[idx] = f2bs(w);
  }
}

// ---- scan of 256 bucket counts -> exclusive bases + cursors ----
__global__ void k_scan256(const unsigned* __restrict__ gcount, unsigned* __restrict__ gbase,
                          unsigned* __restrict__ gcursor){
  __shared__ unsigned t[NB];
  const int i = threadIdx.x;
  const unsigned c = gcount[i];
  t[i] = c;
  __syncthreads();
  for(int off=1; off<NB; off<<=1){
    unsigned v = (i>=off) ? t[i-off] : 0u;
    __syncthreads();
    t[i] += v;
    __syncthreads();
  }
  const unsigned excl = t[i] - c;
  gbase[i] = excl;
  gcursor[i] = excl;
  if(i == NB-1) gbase[NB] = t[NB-1];
}

// ---- bucket scatter: edges -> bucket-grouped (brow, bmeta) ----
// Per block: LDS hist, one global atomic per bucket to claim a range, then
// LDS-cursor scatter. Writes land in ~16-edge runs per (block,bucket).
__global__ __launch_bounds__(256) void k_bucket(const int* __restrict__ rows, const int* __restrict__ cols,
                         const float* __restrict__ vals, unsigned* __restrict__ gcursor,
                         int* __restrict__ brow, int2* __restrict__ bmeta){
  __shared__ unsigned hcnt[NB];
  __shared__ unsigned lcur[NB];
  const int t = threadIdx.x;
  const int base = blockIdx.x*EPT;
  hcnt[t] = 0u;
  __syncthreads();
  int4 r4[4];
#pragma unroll
  for(int k=0;k<4;++k){
    r4[k] = *(const int4*)(rows + base + k*1024 + t*4);
    atomicAdd(&hcnt[(unsigned)r4[k].x/RPB], 1u);
    atomicAdd(&hcnt[(unsigned)r4[k].y/RPB], 1u);
    atomicAdd(&hcnt[(unsigned)r4[k].z/RPB], 1u);
    atomicAdd(&hcnt[(unsigned)r4[k].w/RPB], 1u);
  }
  __syncthreads();
  lcur[t] = atomicAdd(&gcursor[t], hcnt[t]);
  __syncthreads();
#pragma unroll
  for(int k=0;k<4;++k){
    const int4   c4 = *(const int4*)(cols + base + k*1024 + t*4);
    const float4 v4 = *(const float4*)(vals + base + k*1024 + t*4);
    unsigned p;
    p = atomicAdd(&lcur[(unsigned)r4[k].x/RPB],1u); brow[p]=r4[k].x; { int2 m; m.x=c4.x; m.y=__float_as_int(v4.x); bmeta[p]=m; }
    p = atomicAdd(&lcur[(unsigned)r4[k].y/RPB],1u); brow[p]=r4[k].y; { int2 m; m.x=c4.y; m.y=__float_as_int(v4.y); bmeta[p]=m; }
    p = atomicAdd(&lcur[(unsigned)r4[k].z/RPB],1u); brow[p]=r4[k].z; { int2 m; m.x=c4.z; m.y=__float_as_int(v4.z); bmeta[p]=m; }
    p = atomicAdd(&lcur[(unsigned)r4[k].w/RPB],1u); brow[p]=r4[k].w; { int2 m; m.x=c4.w; m.y=__float_as_int(v4.w); bmeta[p]=m; }
  }
}

// ---- per-bucket CSR finalize: one block per bucket, all in LDS ----
// LDS 768-row hist -> chunked scan (3 rows/thread) -> rstart/rend + LDS-rank
// scatter of bmeta into the final row-sorted meta. All global IO streaming.
__global__ __launch_bounds__(256) void k_csr(const int* __restrict__ brow, const int2* __restrict__ bmeta,
                      const unsigned* __restrict__ gbase,
                      unsigned* __restrict__ rstart, unsigned* __restrict__ rend,
                      int2* __restrict__ meta){
  __shared__ unsigned rcnt[RPB];
  __shared__ unsigned rcur[RPB];
  __shared__ unsigned ssum[256];
  const int t = threadIdx.x, b = blockIdx.x;
  const unsigned base = gbase[b];
  const int nb = (int)(gbase[b+1] - base);
  const int rv0 = b*RPB;
#pragma unroll
  for(int k=0;k<3;++k) rcnt[t*3+k] = 0u;
  __syncthreads();
  for(int e=t; e<nb; e+=256){
    const int r = brow[base+e] - rv0;
    atomicAdd(&rcnt[r], 1u);
  }
  __syncthreads();
  const unsigned c0 = rcnt[t*3], c1 = rcnt[t*3+1], c2 = rcnt[t*3+2];
  const unsigned mysum = c0+c1+c2;
  ssum[t] = mysum;
  __syncthreads();
  for(int off=1; off<256; off<<=1){
    unsigned v = (t>=off) ? ssum[t-off] : 0u;
    __syncthreads();
    ssum[t] += v;
    __syncthreads();
  }
  const unsigned excl = ssum[t] - mysum;
  const unsigned s0 = base + excl, s1 = s0 + c0, s2 = s1 + c1;
  rstart[rv0+t*3+0] = s0;  rend[rv0+t*3+0] = s0 + c0;  rcur[t*3+0] = s0;
  rstart[rv0+t*3+1] = s1;  rend[rv0+t*3+1] = s1 + c1;  rcur[t*3+1] = s1;
  rstart[rv0+t*3+2] = s2;  rend[rv0+t*3+2] = s2 + c2;  rcur[t*3+2] = s2;
  __syncthreads();
  for(int e=t; e<nb; e+=256){
    const int r = brow[base+e] - rv0;
    const unsigned pos = atomicAdd(&rcur[r], 1u);
    meta[pos] = bmeta[base+e];
  }
}

// ---------------- gather pipeline macros (R5-proven) ----------------

#define SP_STAGE(U,W,I) { int c_=0; float wv_=0.f; \
    if((I) < n){ const int2 m_ = meta[s+(unsigned)(I)]; c_=m_.x; wv_=__int_as_float(m_.y);} \
    W = wv_; U = *(const u32x4*)(src + (size_t)c_*SROW + off); }
#define SP_CONSUME(U,W) { \
    a0=fmaf(W,lo16(U[0]),a0); a1=fmaf(W,hi16(U[0]),a1); \
    a2=fmaf(W,lo16(U[1]),a2); a3=fmaf(W,hi16(U[1]),a3); \
    a4=fmaf(W,lo16(U[2]),a4); a5=fmaf(W,hi16(U[2]),a5); \
    a6=fmaf(W,lo16(U[3]),a6); a7=fmaf(W,hi16(U[3]),a7); }
#define SP_BODY \
  float a0=0,a1=0,a2=0,a3=0,a4=0,a5=0,a6=0,a7=0; \
  if(nmax > 0){ \
    u32x4 u0,u1,u2,u3; float w0,w1,w2,w3; \
    SP_STAGE(u0,w0,0) SP_STAGE(u1,w1,1) SP_STAGE(u2,w2,2) SP_STAGE(u3,w3,3) \
    int rem = nmax - 4; \
    int j = 4; \
    while(rem > 0){ \
      const u32x4 p0=u0, p1=u1, p2=u2, p3=u3; \
      const float q0=w0, q1=w1, q2=w2, q3=w3; \
      SP_STAGE(u0,w0,j) SP_STAGE(u1,w1,j+1) SP_STAGE(u2,w2,j+2) SP_STAGE(u3,w3,j+3) \
      SP_CONSUME(p0,q0) SP_CONSUME(p1,q1) SP_CONSUME(p2,q2) SP_CONSUME(p3,q3) \
      rem -= 4; j += 4; \
    } \
    SP_CONSUME(u0,w0) SP_CONSUME(u1,w1) SP_CONSUME(u2,w2) SP_CONSUME(u3,w3) \
  } \
  unsigned r0 = ((unsigned)(unsigned short)f2bs(a1)<<16) | (unsigned)(unsigned short)f2bs(a0); \
  unsigned r1 = ((unsigned)(unsigned short)f2bs(a3)<<16) | (unsigned)(unsigned short)f2bs(a2); \
  unsigned r2 = ((unsigned)(unsigned short)f2bs(a5)<<16) | (unsigned)(unsigned short)f2bs(a4); \
  unsigned r3 = ((unsigned)(unsigned short)f2bs(a7)<<16) | (unsigned)(unsigned short)f2bs(a6); \
  u32x4 ov; ov[0]=r0; ov[1]=r1; ov[2]=r2; ov[3]=r3;

// ---------------- SpMM1: TWO rows per wave (one per half-wave) --------------

template<int SROW, size_t PSTR>
__global__ __launch_bounds__(256) void k_spmm(const short* __restrict__ src,
                          const int2* __restrict__ meta,
                          const unsigned* __restrict__ rstart, const unsigned* __restrict__ rend,
                          short* __restrict__ dst){
  const int tid = threadIdx.x;
  const int lane = tid & 63;
  const int half = lane >> 5, sub = lane & 31;
  const int vbase = blockIdx.x*8 + (tid>>6)*2;
  const unsigned sA = rstart[vbase],   sB = rstart[vbase+1];
  const int nA = (int)(rend[vbase]-sA), nB = (int)(rend[vbase+1]-sB);
  const int nmax = (nA > nB) ? nA : nB;
  const unsigned s = half ? sB : sA;
  const int n = half ? nB : nA;
  const size_t off = (size_t)(sub>>4)*PSTR + (size_t)((sub&15)*8);
  SP_BODY
  *(u32x4*)(dst + (size_t)(vbase+half)*256 + sub*8) = ov;
}

// ---------------- fused SpMM2 + MFMA GEMM (R7-proven 16-row slab) ----------
// Each wave owns 16 output rows (m-split): gathers its own y = L@x1 rows into
// a wave-private LDS slab (no __syncthreads anywhere), then computes
// out[b, rows, q] = bias + x0*(W0-W2) + x1*W1 + y*(2W2) via MFMA.
// mfma_f32_16x16x32_bf16: A row=l&15, k=8*(l>>4)+i; C/D col=l&15, row=4*(l>>4)+reg.
// x0c-in-d_out aliasing safe: wave reads x0c only for its own 16 rows and is
// the only writer of those out rows; per-wave program order orders them.

__global__ __launch_bounds__(256) void k_gemm_fused(
    const short* __restrict__ x0, const short* __restrict__ x1,
    const short* __restrict__ wcb, const float* __restrict__ bias,
    const int2* __restrict__ meta, const unsigned* __restrict__ rstart,
    const unsigned* __restrict__ rend, float* __restrict__ out){
  __shared__ short ylds[4][16*264];
  const int t = threadIdx.x, w = t>>6, l = t&63;
  const int half = l>>5, sub = l&31;
  const int vw = blockIdx.x*64 + w*16;
  short* const my = &ylds[w][0];
  const short* const src = x1;
  const int SROW = 256;
  const size_t off = (size_t)(sub>>4)*128 + (size_t)((sub&15)*8);

  // ---- phase 1: gather 16 y-rows (8 pairs, half-wave per row) ----
  for(int pr=0; pr<8; ++pr){
    const int vb = vw + pr*2;
    const unsigned sA = rstart[vb], sB = rstart[vb+1];
    const int nA = (int)(rend[vb]-sA), nB = (int)(rend[vb+1]-sB);
    const int nmax = (nA > nB) ? nA : nB;
    const unsigned s = half ? sB : sA;
    const int n = half ? nB : nA;
    SP_BODY
    *(u32x4*)(my + (pr*2+half)*264 + off) = ov;
  }

  // ---- phase 2: MFMA (wave-local; compiler orders LDS read-after-write) ----
  const int r = l&15, g = l>>4;
  f32x4 acc[4][4] = {};   // [batch][n]
#pragma unroll
  for(int c=0; c<6; ++c){
    const int part = c>>1, ko = (c&1)*32;
    const int kw = part*64 + ko + 8*g;
    const bf16x8 bfr0 = *(const bf16x8*)&wcb[( 0+r)*192 + kw];
    const bf16x8 bfr1 = *(const bf16x8*)&wcb[(16+r)*192 + kw];
    const bf16x8 bfr2 = *(const bf16x8*)&wcb[(32+r)*192 + kw];
    const bf16x8 bfr3 = *(const bf16x8*)&wcb[(48+r)*192 + kw];
#pragma unroll
    for(int bb=0; bb<4; ++bb){
      bf16x8 a;
      if(part==0)      a = *(const bf16x8*)(x0 + ((size_t)(bb>>1)*Vn + vw + r)*128 + (bb&1)*64 + ko + 8*g);
      else if(part==1) a = *(const bf16x8*)(x1 + ((size_t)(vw + r))*256 + bb*64 + ko + 8*g);
      else             a = *(const bf16x8*)(my + r*264 + bb*64 + ko + 8*g);
      acc[bb][0] = __builtin_amdgcn_mfma_f32_16x16x32_bf16(a, bfr0, acc[bb][0], 0, 0, 0);
      acc[bb][1] = __builtin_amdgcn_mfma_f32_16x16x32_bf16(a, bfr1, acc[bb][1], 0, 0, 0);
      acc[bb][2] = __builtin_amdgcn_mfma_f32_16x16x32_bf16(a, bfr2, acc[bb][2], 0, 0, 0);
      acc[bb][3] = __builtin_amdgcn_mfma_f32_16x16x32_bf16(a, bfr3, acc[bb][3], 0, 0, 0);
    }
  }

  // ---- epilogue ----
#pragma unroll
  for(int bb=0; bb<4; ++bb){
    float* ob = out + (size_t)bb*Vn*64;
#pragma unroll
    for(int n=0; n<4; ++n){
      const float bq = bias[n*16+r];
#pragma unroll
      for(int reg=0; reg<4; ++reg)
        ob[(size_t)(vw + g*4 + reg)*64 + n*16 + r] = acc[bb][n][reg] + bq;
    }
  }
}

// ---------------- launch ----------------

extern "C" void kernel_launch(void* const* d_in, const int* in_sizes, int n_in,
                              void* d_out, int out_size, void* d_ws, size_t ws_size,
                              hipStream_t stream){
  const float* lap_vals = (const float*)d_in[0];
  const float* x        = (const float*)d_in[1];
  const float* weight   = (const float*)d_in[2];
  const float* bias     = (const float*)d_in[3];
  const int*   lap_rows = (const int*)d_in[4];
  const int*   lap_cols = (const int*)d_in[5];
  float* out = (float*)d_out;
  short* x0c = (short*)d_out;   // bf16 x0 staged inside the output buffer

  char* w = (char*)d_ws;
  short* x1b = (short*)w;          w += (size_t)Vn*256*sizeof(short);
  int2* meta = (int2*)w;           w += (size_t)NNZn*8;
  int2* bmeta = (int2*)w;          w += (size_t)NNZn*8;
  int*  brow = (int*)w;            w += (size_t)NNZn*4;
  unsigned* rstart = (unsigned*)w; w += (size_t)Vn*4;
  unsigned* rend   = (unsigned*)w; w += (size_t)Vn*4;
  unsigned* gcount = (unsigned*)w; w += NB*4;
  unsigned* gbase  = (unsigned*)w; w += (NB+1)*4;
  unsigned* gcursor= (unsigned*)w; w += NB*4;
  short* wcb = (short*)w;          w += 12288*sizeof(short);

  k_zero256<<<1, 256, 0, stream>>>(gcount);
  k_pre<<<25056, 256, 0, stream>>>(lap_rows, gcount, x, x0c, weight, wcb);
  k_scan256<<<1, 256, 0, stream>>>(gcount, gbase, gcursor);
  k_bucket<<<NTIL, 256, 0, stream>>>(lap_rows, lap_cols, lap_vals, gcursor, brow, bmeta);
  k_csr<<<NB, 256, 0, stream>>>(brow, bmeta, gbase, rstart, rend, meta);

  // x1 = L @ x0   (gather from x0c: piece-split rows, 2 x 256B segments)
  k_spmm<128, (size_t)Vn*128><<<Vn/8, 256, 0, stream>>>(x0c, meta, rstart, rend, x1b);

  // fused: y-gather (L @ x1) + MFMA epilogue
  k_gemm_fused<<<Vn/64, 256, 0, stream>>>(x0c, x1b, wcb, bias,
                                          meta, rstart, rend, out);
}